// Round 14
// baseline (249.538 us; speedup 1.0000x reference)
//
#include <hip/hip_runtime.h>
#include <hip/hip_bf16.h>

#define BB 4
#define SS 2048
#define DD 1024
#define HH 16
#define HDD 64
#define MM (BB*SS)   // 8192

using bf16x8 = __attribute__((ext_vector_type(8))) short;
using f32x4  = __attribute__((ext_vector_type(4))) float;
using f32x16 = __attribute__((ext_vector_type(16))) float;

static __device__ __forceinline__ ushort f2bf(float f) {
    __hip_bfloat16 h = __float2bfloat16(f);
    return *reinterpret_cast<ushort*>(&h);
}

// async global->LDS, 16B per lane; LDS dest = wave-uniform base + lane*16
static __device__ __forceinline__ void gload_lds16(const ushort* g, ushort* l) {
    __builtin_amdgcn_global_load_lds(
        (const __attribute__((address_space(1))) unsigned int*)g,
        (__attribute__((address_space(3))) unsigned int*)l, 16, 0, 0);
}

// packed f32x2 -> bf16x2 (src0 -> low 16), RNE
static __device__ __forceinline__ unsigned cvtpk(float lo, float hi) {
    unsigned r;
    asm("v_cvt_pk_bf16_f32 %0, %1, %2" : "=v"(r) : "v"(lo), "v"(hi));
    return r;
}

// raw v_exp_f32: computes 2^x
static __device__ __forceinline__ float exp2_raw(float x) {
    float r;
    asm("v_exp_f32 %0, %1" : "=v"(r) : "v"(x));
    return r;
}

// exchange a's hi-half lanes with b's lo-half lanes (both outputs usable)
static __device__ __forceinline__ void halfswap(unsigned& a, unsigned& b, int hi) {
#if __has_builtin(__builtin_amdgcn_permlane32_swap)
    typedef int v2i __attribute__((ext_vector_type(2)));
    v2i r = __builtin_amdgcn_permlane32_swap((int)a, (int)b, false, false);
    a = (unsigned)r.x; b = (unsigned)r.y;
#else
    unsigned xa = (unsigned)__shfl_xor((int)a, 32);
    unsigned xb = (unsigned)__shfl_xor((int)b, 32);
    unsigned na = hi ? xb : a;
    unsigned nb = hi ? b : xa;
    a = na; b = nb;
#endif
}

// counted vmcnt wait + raw barrier: never reorder memory ops across
#define PIPE_BAR(N) do {                                          \
    asm volatile("s_waitcnt vmcnt(" #N ")" ::: "memory");         \
    __builtin_amdgcn_sched_barrier(0);                            \
    __builtin_amdgcn_s_barrier();                                 \
    __builtin_amdgcn_sched_barrier(0);                            \
} while (0)

// ---------------------------------------------------------------------------
// weight transpose+cast: W[1024][1024] fp32 -> W^T[1024][1024] bf16
// ---------------------------------------------------------------------------
__global__ __launch_bounds__(256) void wtrans_k(
    const float* __restrict__ w0, const float* __restrict__ w1,
    const float* __restrict__ w2, const float* __restrict__ w3,
    ushort* __restrict__ o0, ushort* __restrict__ o1,
    ushort* __restrict__ o2, ushort* __restrict__ o3)
{
    __shared__ float tile[32][33];
    const float* W; ushort* O;
    switch (blockIdx.z) {
        case 0:  W = w0; O = o0; break;
        case 1:  W = w1; O = o1; break;
        case 2:  W = w2; O = o2; break;
        default: W = w3; O = o3; break;
    }
    const int tx = threadIdx.x & 31, ty = threadIdx.x >> 5;   // 32 x 8
    const int n0 = blockIdx.x * 32, k0 = blockIdx.y * 32;
    #pragma unroll
    for (int i = 0; i < 4; i++)
        tile[ty * 4 + i][tx] = W[(size_t)(k0 + ty * 4 + i) * DD + n0 + tx];
    __syncthreads();
    #pragma unroll
    for (int i = 0; i < 4; i++)
        O[(size_t)(n0 + ty * 4 + i) * DD + k0 + tx] = f2bf(tile[tx][ty * 4 + i]);
}

// ---------------------------------------------------------------------------
// Fused QKV GEMM, fp32-A in-flight cast. Grid = 1536 = 3 segs x 512 blocks.
// r9 structure (128x128 tile, 4 waves 2x2 of 64x64, high occupancy) with
// BK=64: half the barrier/waitcnt events per MFMA (16 K-steps of 32 MFMA
// vs 32 steps of 16). LDS 34 KB -> still 4 blocks/CU.
// FIFO per step: entry has A(t)[8] outstanding (compiler drains at the
// cvt that consumes them); issue B(t)[4], then A(t+1)[8]; vmcnt(8)
// retires exactly B(t), leaving A(t+1) in flight across the MFMAs.
//   seg 0: Q -> bf16 head-split [B,H,S,HD], x(0.125*log2e)
//   seg 1: K -> bf16 head-split
//   seg 2: V -> bf16 transposed head-split [B,H,HD,S]
// ---------------------------------------------------------------------------
__global__ __launch_bounds__(256) void gemm_qkv_k(
    const float* __restrict__ qi, const float* __restrict__ ki,
    const float* __restrict__ vi,
    const ushort* __restrict__ wqT, const ushort* __restrict__ wkT,
    const ushort* __restrict__ wvT,
    const float* __restrict__ b_q, const float* __restrict__ b_k,
    const float* __restrict__ b_v,
    ushort* __restrict__ qo, ushort* __restrict__ ko, ushort* __restrict__ vo)
{
    __shared__ ushort As[128 * 72];   // padded: row stride 72 elems = 144 B
    __shared__ ushort Bs[128 * 64];   // linear (gload_lds dest), 16 KB

    const int seg = blockIdx.x >> 9;            // 0=q,1=k,2=v
    int bid = blockIdx.x & 511;
    bid = (bid & 7) * 64 + (bid >> 3);          // XCD swizzle (512%8==0)
    const int mt = bid >> 3, nt = bid & 7;
    const int m0 = mt * 128, n0 = nt * 128;

    const float*  A32  = seg == 0 ? qi  : seg == 1 ? ki  : vi;
    const ushort* WT   = seg == 0 ? wqT : seg == 1 ? wkT : wvT;
    const float*  bias = seg == 0 ? b_q : seg == 1 ? b_k : b_v;
    ushort*       Cout = seg == 0 ? qo  : seg == 1 ? ko  : vo;
    const float   sc   = seg == 0 ? 0.180336880111f : 1.0f;

    const int t  = threadIdx.x;
    const int w  = t >> 6;
    const int l  = t & 63;
    const int lr = l & 15;
    const int lg = l >> 4;
    const int wr = w >> 1, wc = w & 1;

    // A staging: thread t -> row t>>1 (0..127), col base (t&1)*32
    const int ar = t >> 1;
    const int ac = (t & 1) * 32;

    f32x4 acc[4][4];
    #pragma unroll
    for (int mi = 0; mi < 4; mi++)
        #pragma unroll
        for (int ni = 0; ni < 4; ni++)
            acc[mi][ni] = (f32x4){0.f, 0.f, 0.f, 0.f};

    const float*  Ab = A32 + (size_t)m0 * DD;
    const ushort* Bb = WT  + (size_t)n0 * DD;

    // prologue A(0) load: 8 float4 in flight
    f32x4 av[8];
    #pragma unroll
    for (int j = 0; j < 8; j++)
        av[j] = *(const f32x4*)(Ab + (size_t)ar * DD + ac + j * 4);

    for (int k0 = 0; k0 < DD; k0 += 64) {
        __builtin_amdgcn_s_barrier();      // prev step's LDS reads consumed
        // ---- A: cvt + 4x ds_write_b128 (compiler drains A(t) loads here) ----
        #pragma unroll
        for (int j = 0; j < 4; j++) {
            union { unsigned u[4]; bf16x8 v8; } fr;
            fr.u[0] = cvtpk(av[2*j].x, av[2*j].y);
            fr.u[1] = cvtpk(av[2*j].z, av[2*j].w);
            fr.u[2] = cvtpk(av[2*j+1].x, av[2*j+1].y);
            fr.u[3] = cvtpk(av[2*j+1].z, av[2*j+1].w);
            *(bf16x8*)&As[ar * 72 + ac + j * 8] = fr.v8;
        }
        // ---- B(t): 4 async gloads per thread (wave-uniform base + lane*16) ----
        #pragma unroll
        for (int j = 0; j < 4; j++) {
            const int c = w * 256 + j * 64 + l;     // chunk id 0..1023
            const int srow = c >> 3;
            const int scol = (c & 7) * 8;
            gload_lds16(Bb + (size_t)srow * DD + k0 + scol, &Bs[c * 8]);
        }
        __builtin_amdgcn_sched_barrier(0);   // pin: B issued before A-prefetch
        // ---- A(t+1) prefetch: always 8 loads so the vmcnt count is exact ----
        {
            const int kn = (k0 + 64 < DD) ? k0 + 64 : 0;
            #pragma unroll
            for (int j = 0; j < 8; j++)
                av[j] = *(const f32x4*)(Ab + (size_t)ar * DD + kn + ac + j * 4);
        }
        // retire B(t)[4] + ds_writes; keep A(t+1)[8] flying
        asm volatile("s_waitcnt vmcnt(8) lgkmcnt(0)" ::: "memory");
        __builtin_amdgcn_sched_barrier(0);
        __builtin_amdgcn_s_barrier();
        __builtin_amdgcn_sched_barrier(0);

        // ---- fragments + MFMA: 2 k-sub-steps of 16 ----
        #pragma unroll
        for (int kk = 0; kk < 2; kk++) {
            bf16x8 af[4], bfr[4];
            #pragma unroll
            for (int mi = 0; mi < 4; mi++)
                af[mi] = *(const bf16x8*)
                    &As[(wr * 64 + mi * 16 + lr) * 72 + kk * 32 + lg * 8];
            #pragma unroll
            for (int ni = 0; ni < 4; ni++)
                bfr[ni] = *(const bf16x8*)
                    &Bs[(wc * 64 + ni * 16 + lr) * 64 + kk * 32 + lg * 8];
            #pragma unroll
            for (int mi = 0; mi < 4; mi++)
                #pragma unroll
                for (int ni = 0; ni < 4; ni++)
                    acc[mi][ni] = __builtin_amdgcn_mfma_f32_16x16x32_bf16(
                        af[mi], bfr[ni], acc[mi][ni], 0, 0, 0);
        }
    }

    // ---- epilogue ----
    #pragma unroll
    for (int mi = 0; mi < 4; mi++) {
        #pragma unroll
        for (int ni = 0; ni < 4; ni++) {
            const int c  = n0 + wc * 64 + ni * 16 + lr;
            const float bc = bias[c];
            const int r0 = m0 + wr * 64 + mi * 16 + lg * 4;
            if (seg == 2) {
                const int bi = r0 >> 11, si = r0 & 2047;
                const int hi = c >> 6,  hd = c & 63;
                ushort pk[4];
                #pragma unroll
                for (int rg = 0; rg < 4; rg++)
                    pk[rg] = f2bf(acc[mi][ni][rg] + bc);
                *(uint2*)&Cout[(((size_t)(bi * HH + hi) * HDD) + hd) * SS + si] =
                    *(const uint2*)pk;
            } else {
                #pragma unroll
                for (int rg = 0; rg < 4; rg++) {
                    const int r = r0 + rg;
                    const int bi = r >> 11, si = r & 2047;
                    const int hi = c >> 6,  hd = c & 63;
                    Cout[(((size_t)(bi * HH + hi) * SS) + si) * HDD + hd] =
                        f2bf((acc[mi][ni][rg] + bc) * sc);
                }
            }
        }
    }
}

// ---------------------------------------------------------------------------
// bf16 MFMA GEMM (m97 template), out-projection only (unchanged)
// ---------------------------------------------------------------------------
__global__ __launch_bounds__(256) void gemm_out_k(
    const ushort* __restrict__ A, const ushort* __restrict__ WT,
    const float* __restrict__ bias, float* __restrict__ Cout)
{
    __shared__ ushort As[128 * 32];
    __shared__ ushort Bs[128 * 32];

    const int t  = threadIdx.x;
    const int w  = t >> 6;
    const int l  = t & 63;
    const int lr = l & 15;
    const int lg = l >> 4;
    const int wr = w >> 1, wc = w & 1;

    int bid = blockIdx.x;
    bid = (bid & 7) * 64 + (bid >> 3);
    const int mt = bid >> 3, nt = bid & 7;
    const int m0 = mt * 128, n0 = nt * 128;

    const int srow = l >> 2;
    const int scol = (l & 3) * 8;

    f32x4 acc[4][4];
    #pragma unroll
    for (int mi = 0; mi < 4; mi++)
        #pragma unroll
        for (int ni = 0; ni < 4; ni++)
            acc[mi][ni] = (f32x4){0.f, 0.f, 0.f, 0.f};

    const ushort* Ab = A  + (size_t)m0 * DD;
    const ushort* Bb = WT + (size_t)n0 * DD;

    for (int k0 = 0; k0 < DD; k0 += 32) {
        __syncthreads();
        #pragma unroll
        for (int j = 0; j < 2; j++) {
            const int rbase = (w * 2 + j) * 16;
            gload_lds16(Ab + (size_t)(rbase + srow) * DD + k0 + scol, &As[rbase * 32]);
            gload_lds16(Bb + (size_t)(rbase + srow) * DD + k0 + scol, &Bs[rbase * 32]);
        }
        __syncthreads();

        bf16x8 af[4], bfr[4];
        #pragma unroll
        for (int mi = 0; mi < 4; mi++)
            af[mi] = *(const bf16x8*)&As[(wr * 64 + mi * 16 + lr) * 32 + lg * 8];
        #pragma unroll
        for (int ni = 0; ni < 4; ni++)
            bfr[ni] = *(const bf16x8*)&Bs[(wc * 64 + ni * 16 + lr) * 32 + lg * 8];
        #pragma unroll
        for (int mi = 0; mi < 4; mi++)
            #pragma unroll
            for (int ni = 0; ni < 4; ni++)
                acc[mi][ni] = __builtin_amdgcn_mfma_f32_16x16x32_bf16(
                    af[mi], bfr[ni], acc[mi][ni], 0, 0, 0);
    }

    #pragma unroll
    for (int mi = 0; mi < 4; mi++) {
        #pragma unroll
        for (int ni = 0; ni < 4; ni++) {
            const int c  = n0 + wc * 64 + ni * 16 + lr;
            const float bc = bias[c];
            const int r0 = m0 + wr * 64 + mi * 16 + lg * 4;
            #pragma unroll
            for (int rg = 0; rg < 4; rg++)
                Cout[(size_t)(r0 + rg) * DD + c] = acc[mi][ni][rg] + bc;
        }
    }
}

// ---------------------------------------------------------------------------
// 4-warp swapped-QK^T flash attention, 64 q-rows/wave (2 q-groups).
// EXACT round-8 kernel (measured 84.7 us; best of 6 attn structure variants)
// ---------------------------------------------------------------------------
__global__ __launch_bounds__(256, 2) void flash_attn_mfma(
    const ushort* __restrict__ qh, const ushort* __restrict__ kh,
    const ushort* __restrict__ vt, ushort* __restrict__ ctx)
{
    __shared__ ushort smem[16384];   // K: 2x4096 | V: 2x4096 = 32 KB

    const int t  = threadIdx.x;
    const int w  = t >> 6;          // warp 0..3
    const int l  = t & 63;
    const int hi = l >> 5;          // half index
    const int lq = l & 31;          // q col / kv row / d row selector

    // bijective XCD-chunk swizzle: 512 wgs = 8 XCDs x 64
    const int wg = (blockIdx.x & 7) * 64 + (blockIdx.x >> 3);
    const int bi = wg >> 7;
    const int h  = (wg >> 3) & 15;
    const int q0 = (wg & 7) * 256;

    const size_t base  = (size_t)(bi * HH + h) * SS * HDD;  // [S][HD]
    const size_t basev = (size_t)(bi * HH + h) * HDD * SS;  // [HD][S]

    // Q B-frags, 2 q-groups: lane holds Q[q0+w*64+qg*32+lq][ds*16+hi*8+i]
    bf16x8 qf0[4], qf1[4];
    {
        const ushort* qp0 = qh + base + (size_t)(q0 + w * 64 + lq) * HDD;
        const ushort* qp1 = qp0 + 32 * HDD;
        #pragma unroll
        for (int ds = 0; ds < 4; ds++) {
            qf0[ds] = *(const bf16x8*)(qp0 + ds * 16 + hi * 8);
            qf1[ds] = *(const bf16x8*)(qp1 + ds * 16 + hi * 8);
        }
    }

    f32x16 o00 = {}, o01 = {}, o10 = {}, o11 = {};  // o[qg][d-half]
    float l0 = 0.f, l1 = 0.f;      // lane-local p-sums per q-group

    const int rsub = l >> 3;                    // 0..7
    const int csw  = ((l & 7) ^ rsub) * 8;      // pre-swizzled 16B chunk
    auto stageK = [&](int buf, int kv) {
        #pragma unroll
        for (int j = 0; j < 2; j++) {
            const int rb = 16 * w + 8 * j;
            gload_lds16(kh + base + (size_t)(kv + rb + rsub) * HDD + csw,
                        &smem[buf * 4096 + rb * 64]);
        }
    };
    auto stageV = [&](int buf, int kv) {
        #pragma unroll
        for (int j = 0; j < 2; j++) {
            const int rb = 16 * w + 8 * j;
            gload_lds16(vt + basev + (size_t)(rb + rsub) * SS + kv + csw,
                        &smem[8192 + buf * 4096 + rb * 64]);
        }
    };

    auto qk2 = [&](const ushort* KB, int kvh, f32x16& sg0, f32x16& sg1) {
        sg0 = (f32x16){};
        sg1 = (f32x16){};
        __builtin_amdgcn_s_setprio(1);
        #pragma unroll
        for (int ds = 0; ds < 4; ds++) {
            const int slot = ((ds * 2 + hi) ^ (l & 7)) * 8;
            bf16x8 ka = *(const bf16x8*)&KB[(kvh * 32 + lq) * 64 + slot];
            sg0 = __builtin_amdgcn_mfma_f32_32x32x16_bf16(ka, qf0[ds], sg0, 0, 0, 0);
            sg1 = __builtin_amdgcn_mfma_f32_32x32x16_bf16(ka, qf1[ds], sg1, 0, 0, 0);
        }
        __builtin_amdgcn_s_setprio(0);
    };

    auto finish16 = [&](f32x16& s, float& lacc, bf16x8* pa2) {
        float t0 = 0.f, t1 = 0.f, t2 = 0.f, t3 = 0.f;
        #pragma unroll
        for (int r = 0; r < 16; r += 4) {
            s[r + 0] = exp2_raw(s[r + 0]); t0 += s[r + 0];
            s[r + 1] = exp2_raw(s[r + 1]); t1 += s[r + 1];
            s[r + 2] = exp2_raw(s[r + 2]); t2 += s[r + 2];
            s[r + 3] = exp2_raw(s[r + 3]); t3 += s[r + 3];
        }
        lacc += (t0 + t1) + (t2 + t3);
        #pragma unroll
        for (int sblk = 0; sblk < 2; sblk++) {
            const int ob = sblk * 8;
            unsigned a = cvtpk(s[ob + 0], s[ob + 1]);
            unsigned b = cvtpk(s[ob + 4], s[ob + 5]);
            halfswap(a, b, hi);
            unsigned c = cvtpk(s[ob + 2], s[ob + 3]);
            unsigned d = cvtpk(s[ob + 6], s[ob + 7]);
            halfswap(c, d, hi);
            union { unsigned u[4]; bf16x8 v; } fr;
            fr.u[0] = a; fr.u[1] = c; fr.u[2] = b; fr.u[3] = d;
            pa2[sblk] = fr.v;
        }
    };

    auto pvhalf = [&](const ushort* VB, int kvh,
                      const bf16x8* pg0, const bf16x8* pg1) {
        __builtin_amdgcn_s_setprio(1);
        #pragma unroll
        for (int ksl = 0; ksl < 2; ksl++) {
            const int ks = kvh * 2 + ksl;
            const int slot = ((ks * 2 + hi) ^ (l & 7)) * 8;
            bf16x8 vb0 = *(const bf16x8*)&VB[lq * 64 + slot];
            bf16x8 vb1 = *(const bf16x8*)&VB[(32 + lq) * 64 + slot];
            o00 = __builtin_amdgcn_mfma_f32_32x32x16_bf16(pg0[ksl], vb0, o00, 0, 0, 0);
            o01 = __builtin_amdgcn_mfma_f32_32x32x16_bf16(pg0[ksl], vb1, o01, 0, 0, 0);
            o10 = __builtin_amdgcn_mfma_f32_32x32x16_bf16(pg1[ksl], vb0, o10, 0, 0, 0);
            o11 = __builtin_amdgcn_mfma_f32_32x32x16_bf16(pg1[ksl], vb1, o11, 0, 0, 0);
        }
        __builtin_amdgcn_s_setprio(0);
    };

    stageK(0, 0); stageV(0, 0);
    int cur = 0;

    for (int tt = 0; tt < 32; tt++) {
        PIPE_BAR(0);                 // tile tt in LDS (staged a full tile ago)
        if (tt + 1 < 32) { stageK(cur ^ 1, (tt + 1) * 64);
                           stageV(cur ^ 1, (tt + 1) * 64); }

        const ushort* KB = &smem[cur * 4096];
        const ushort* VB = &smem[8192 + cur * 4096];

        f32x16 sA, sB, sC, sD;       // h0:{g0,g1}, h1:{g0,g1}
        qk2(KB, 0, sA, sB);
        qk2(KB, 1, sC, sD);

        bf16x8 pg0[2], pg1[2];
        finish16(sA, l0, pg0);
        finish16(sB, l1, pg1);
        pvhalf(VB, 0, pg0, pg1);
        finish16(sC, l0, pg0);
        finish16(sD, l1, pg1);
        pvhalf(VB, 1, pg0, pg1);

        cur ^= 1;
    }

    const float ls0 = l0 + __shfl_xor(l0, 32);
    const float ls1 = l1 + __shfl_xor(l1, 32);
    const float iv0 = 1.0f / ls0;
    const float iv1 = 1.0f / ls1;
    #pragma unroll
    for (int r = 0; r < 16; r++) {
        const int qq = (r & 3) + 8 * (r >> 2) + 4 * hi;   // crow(r,hi)
        const float a0 = __shfl(iv0, qq);
        const float a1 = __shfl(iv1, qq);
        const int row0 = q0 + w * 64 + qq;
        ushort* op0 = ctx + (size_t)(bi * SS + row0) * DD + h * HDD;
        op0[lq]      = f2bf(o00[r] * a0);
        op0[32 + lq] = f2bf(o01[r] * a0);
        ushort* op1 = op0 + (size_t)32 * DD;
        op1[lq]      = f2bf(o10[r] * a1);
        op1[32 + lq] = f2bf(o11[r] * a1);
    }
}

// ---------------------------------------------------------------------------
extern "C" void kernel_launch(void* const* d_in, const int* in_sizes, int n_in,
                              void* d_out, int out_size, void* d_ws, size_t ws_size,
                              hipStream_t stream) {
    const float* q   = (const float*)d_in[0];
    const float* k   = (const float*)d_in[1];
    const float* v   = (const float*)d_in[2];
    const float* w_q = (const float*)d_in[3];
    const float* b_q = (const float*)d_in[4];
    const float* w_k = (const float*)d_in[5];
    const float* b_k = (const float*)d_in[6];
    const float* w_v = (const float*)d_in[7];
    const float* b_v = (const float*)d_in[8];
    const float* w_o = (const float*)d_in[9];
    const float* b_o = (const float*)d_in[10];
    float* out = (float*)d_out;

    const size_t SZ = (size_t)BB * SS * DD;   // 8388608
    const size_t WZ = (size_t)DD * DD;        // 1048576
    ushort* ws2  = (ushort*)d_ws;
    ushort* qh   = ws2;             // bf16 [B,H,S,HD], pre-scaled
    ushort* kh   = ws2 + SZ;        // bf16 [B,H,S,HD]
    ushort* vt   = ws2 + 2 * SZ;    // bf16 [B,H,HD,S]
    ushort* ctxb = ws2 + 3 * SZ;    // bf16 [B,S,D]
    ushort* wqT  = ws2 + 4 * SZ;    // bf16 [N][K]
    ushort* wkT  = wqT + WZ;
    ushort* wvT  = wkT + WZ;
    ushort* woT  = wvT + WZ;

    wtrans_k<<<dim3(32, 32, 4), 256, 0, stream>>>(w_q, w_k, w_v, w_o,
                                                  wqT, wkT, wvT, woT);

    gemm_qkv_k<<<dim3(1536), 256, 0, stream>>>(q, k, v, wqT, wkT, wvT,
                                               b_q, b_k, b_v, qh, kh, vt);

    flash_attn_mfma<<<dim3(512), 256, 0, stream>>>(qh, kh, vt, ctxb);

    gemm_out_k<<<dim3(512), 256, 0, stream>>>(ctxb, woT, b_o, out);
}

// Round 15
// 182.472 us; speedup vs baseline: 1.3675x; 1.3675x over previous
//
#include <hip/hip_runtime.h>
#include <hip/hip_bf16.h>

#define BB 4
#define SS 2048
#define DD 1024
#define HH 16
#define HDD 64
#define MM (BB*SS)   // 8192

using bf16x8 = __attribute__((ext_vector_type(8))) short;
using f32x4  = __attribute__((ext_vector_type(4))) float;
using f32x16 = __attribute__((ext_vector_type(16))) float;

static __device__ __forceinline__ ushort f2bf(float f) {
    __hip_bfloat16 h = __float2bfloat16(f);
    return *reinterpret_cast<ushort*>(&h);
}

// async global->LDS, 16B per lane; LDS dest = wave-uniform base + lane*16
static __device__ __forceinline__ void gload_lds16(const ushort* g, ushort* l) {
    __builtin_amdgcn_global_load_lds(
        (const __attribute__((address_space(1))) unsigned int*)g,
        (__attribute__((address_space(3))) unsigned int*)l, 16, 0, 0);
}

// packed f32x2 -> bf16x2 (src0 -> low 16), RNE
static __device__ __forceinline__ unsigned cvtpk(float lo, float hi) {
    unsigned r;
    asm("v_cvt_pk_bf16_f32 %0, %1, %2" : "=v"(r) : "v"(lo), "v"(hi));
    return r;
}

// raw v_exp_f32: computes 2^x
static __device__ __forceinline__ float exp2_raw(float x) {
    float r;
    asm("v_exp_f32 %0, %1" : "=v"(r) : "v"(x));
    return r;
}

// exchange a's hi-half lanes with b's lo-half lanes (both outputs usable)
static __device__ __forceinline__ void halfswap(unsigned& a, unsigned& b, int hi) {
#if __has_builtin(__builtin_amdgcn_permlane32_swap)
    typedef int v2i __attribute__((ext_vector_type(2)));
    v2i r = __builtin_amdgcn_permlane32_swap((int)a, (int)b, false, false);
    a = (unsigned)r.x; b = (unsigned)r.y;
#else
    unsigned xa = (unsigned)__shfl_xor((int)a, 32);
    unsigned xb = (unsigned)__shfl_xor((int)b, 32);
    unsigned na = hi ? xb : a;
    unsigned nb = hi ? b : xa;
    a = na; b = nb;
#endif
}

// counted vmcnt wait + raw barrier: never reorder memory ops across
#define PIPE_BAR(N) do {                                          \
    asm volatile("s_waitcnt vmcnt(" #N ")" ::: "memory");         \
    __builtin_amdgcn_sched_barrier(0);                            \
    __builtin_amdgcn_s_barrier();                                 \
    __builtin_amdgcn_sched_barrier(0);                            \
} while (0)

// ---------------------------------------------------------------------------
// weight transpose+cast: W[1024][1024] fp32 -> W^T[1024][1024] bf16
// ---------------------------------------------------------------------------
__global__ __launch_bounds__(256) void wtrans_k(
    const float* __restrict__ w0, const float* __restrict__ w1,
    const float* __restrict__ w2, const float* __restrict__ w3,
    ushort* __restrict__ o0, ushort* __restrict__ o1,
    ushort* __restrict__ o2, ushort* __restrict__ o3)
{
    __shared__ float tile[32][33];
    const float* W; ushort* O;
    switch (blockIdx.z) {
        case 0:  W = w0; O = o0; break;
        case 1:  W = w1; O = o1; break;
        case 2:  W = w2; O = o2; break;
        default: W = w3; O = o3; break;
    }
    const int tx = threadIdx.x & 31, ty = threadIdx.x >> 5;   // 32 x 8
    const int n0 = blockIdx.x * 32, k0 = blockIdx.y * 32;
    #pragma unroll
    for (int i = 0; i < 4; i++)
        tile[ty * 4 + i][tx] = W[(size_t)(k0 + ty * 4 + i) * DD + n0 + tx];
    __syncthreads();
    #pragma unroll
    for (int i = 0; i < 4; i++)
        O[(size_t)(n0 + ty * 4 + i) * DD + k0 + tx] = f2bf(tile[tx][ty * 4 + i]);
}

// ---------------------------------------------------------------------------
// Fused QKV GEMM, fp32-A in-flight cast. Grid = 1536 = 3 segs x 512 blocks.
// EXACT round-9 kernel (best measured: total 183.0 us in that config).
//   seg 0: Q -> bf16 head-split [B,H,S,HD], x(0.125*log2e)
//   seg 1: K -> bf16 head-split [B,H,S,HD]
//   seg 2: V -> bf16 transposed head-split [B,H,HD,S]
// A: reg-staged (float4 x4 -> cvt_pk -> ds_write_b128) into padded
// As[128][40] (80B row stride). A-regs double-buffered; prefetch issued
// AFTER the 2 B gload_lds16 (order pinned by sched_barrier) so
// s_waitcnt vmcnt(4) retires exactly the B stages and leaves the 4
// A-prefetch loads in flight across the MFMA section.
// ---------------------------------------------------------------------------
__global__ __launch_bounds__(256) void gemm_qkv_k(
    const float* __restrict__ qi, const float* __restrict__ ki,
    const float* __restrict__ vi,
    const ushort* __restrict__ wqT, const ushort* __restrict__ wkT,
    const ushort* __restrict__ wvT,
    const float* __restrict__ b_q, const float* __restrict__ b_k,
    const float* __restrict__ b_v,
    ushort* __restrict__ qo, ushort* __restrict__ ko, ushort* __restrict__ vo)
{
    __shared__ ushort As[128 * 40];   // padded: row stride 40 elems = 80 B
    __shared__ ushort Bs[128 * 32];   // linear (gload_lds dest)

    const int seg = blockIdx.x >> 9;            // 0=q,1=k,2=v
    int bid = blockIdx.x & 511;
    bid = (bid & 7) * 64 + (bid >> 3);          // XCD swizzle (512%8==0)
    const int mt = bid >> 3, nt = bid & 7;
    const int m0 = mt * 128, n0 = nt * 128;

    const float*  A32  = seg == 0 ? qi  : seg == 1 ? ki  : vi;
    const ushort* WT   = seg == 0 ? wqT : seg == 1 ? wkT : wvT;
    const float*  bias = seg == 0 ? b_q : seg == 1 ? b_k : b_v;
    ushort*       Cout = seg == 0 ? qo  : seg == 1 ? ko  : vo;
    const float   sc   = seg == 0 ? 0.180336880111f : 1.0f;

    const int t  = threadIdx.x;
    const int w  = t >> 6;
    const int l  = t & 63;
    const int lr = l & 15;
    const int lg = l >> 4;
    const int wr = w >> 1, wc = w & 1;

    const int ar = t >> 2;
    const int ac = (t & 3) * 8;
    const int srow = l >> 2;
    const int scol = (l & 3) * 8;

    f32x4 acc[4][4];
    #pragma unroll
    for (int mi = 0; mi < 4; mi++)
        #pragma unroll
        for (int ni = 0; ni < 4; ni++)
            acc[mi][ni] = (f32x4){0.f, 0.f, 0.f, 0.f};

    const float*  Ab = A32 + (size_t)m0 * DD;
    const ushort* Bb = WT  + (size_t)n0 * DD;

    float4 a0[2], a1[2];
    #pragma unroll
    for (int j = 0; j < 2; j++) {
        const float* p = Ab + (size_t)(ar + 64 * j) * DD + ac;
        a0[j] = *(const float4*)p;
        a1[j] = *(const float4*)(p + 4);
    }

    for (int k0 = 0; k0 < DD; k0 += 32) {
        __builtin_amdgcn_s_barrier();      // prev tile's LDS reads consumed
        #pragma unroll
        for (int j = 0; j < 2; j++) {
            union { unsigned u[4]; bf16x8 v8; } fr;
            fr.u[0] = cvtpk(a0[j].x, a0[j].y);
            fr.u[1] = cvtpk(a0[j].z, a0[j].w);
            fr.u[2] = cvtpk(a1[j].x, a1[j].y);
            fr.u[3] = cvtpk(a1[j].z, a1[j].w);
            *(bf16x8*)&As[(ar + 64 * j) * 40 + ac] = fr.v8;
        }
        #pragma unroll
        for (int j = 0; j < 2; j++) {
            const int rbase = (w * 2 + j) * 16;
            gload_lds16(Bb + (size_t)(rbase + srow) * DD + k0 + scol,
                        &Bs[rbase * 32]);
        }
        __builtin_amdgcn_sched_barrier(0);   // pin: B issued before A-prefetch
        {
            const int kn = (k0 + 32 < DD) ? k0 + 32 : 0;
            #pragma unroll
            for (int j = 0; j < 2; j++) {
                const float* p = Ab + (size_t)(ar + 64 * j) * DD + kn + ac;
                a0[j] = *(const float4*)p;
                a1[j] = *(const float4*)(p + 4);
            }
        }
        asm volatile("s_waitcnt vmcnt(4) lgkmcnt(0)" ::: "memory");
        __builtin_amdgcn_sched_barrier(0);
        __builtin_amdgcn_s_barrier();
        __builtin_amdgcn_sched_barrier(0);

        bf16x8 af[4], bfr[4];
        #pragma unroll
        for (int mi = 0; mi < 4; mi++)
            af[mi] = *(const bf16x8*)&As[(wr * 64 + mi * 16 + lr) * 40 + lg * 8];
        #pragma unroll
        for (int ni = 0; ni < 4; ni++)
            bfr[ni] = *(const bf16x8*)&Bs[(wc * 64 + ni * 16 + lr) * 32 + lg * 8];
        #pragma unroll
        for (int mi = 0; mi < 4; mi++)
            #pragma unroll
            for (int ni = 0; ni < 4; ni++)
                acc[mi][ni] = __builtin_amdgcn_mfma_f32_16x16x32_bf16(
                    af[mi], bfr[ni], acc[mi][ni], 0, 0, 0);
    }

    #pragma unroll
    for (int mi = 0; mi < 4; mi++) {
        #pragma unroll
        for (int ni = 0; ni < 4; ni++) {
            const int c  = n0 + wc * 64 + ni * 16 + lr;
            const float bc = bias[c];
            const int r0 = m0 + wr * 64 + mi * 16 + lg * 4;
            if (seg == 2) {
                const int bi = r0 >> 11, si = r0 & 2047;
                const int hi = c >> 6,  hd = c & 63;
                ushort pk[4];
                #pragma unroll
                for (int rg = 0; rg < 4; rg++)
                    pk[rg] = f2bf(acc[mi][ni][rg] + bc);
                *(uint2*)&Cout[(((size_t)(bi * HH + hi) * HDD) + hd) * SS + si] =
                    *(const uint2*)pk;
            } else {
                #pragma unroll
                for (int rg = 0; rg < 4; rg++) {
                    const int r = r0 + rg;
                    const int bi = r >> 11, si = r & 2047;
                    const int hi = c >> 6,  hd = c & 63;
                    Cout[(((size_t)(bi * HH + hi) * SS) + si) * HDD + hd] =
                        f2bf((acc[mi][ni][rg] + bc) * sc);
                }
            }
        }
    }
}

// ---------------------------------------------------------------------------
// bf16 MFMA GEMM (m97 template), out-projection only:
// out_fp32[8192,1024] = ctx_bf16 @ woT^T + b_o
// ---------------------------------------------------------------------------
__global__ __launch_bounds__(256) void gemm_out_k(
    const ushort* __restrict__ A, const ushort* __restrict__ WT,
    const float* __restrict__ bias, float* __restrict__ Cout)
{
    __shared__ ushort As[128 * 32];
    __shared__ ushort Bs[128 * 32];

    const int t  = threadIdx.x;
    const int w  = t >> 6;
    const int l  = t & 63;
    const int lr = l & 15;
    const int lg = l >> 4;
    const int wr = w >> 1, wc = w & 1;

    int bid = blockIdx.x;
    bid = (bid & 7) * 64 + (bid >> 3);
    const int mt = bid >> 3, nt = bid & 7;
    const int m0 = mt * 128, n0 = nt * 128;

    const int srow = l >> 2;
    const int scol = (l & 3) * 8;

    f32x4 acc[4][4];
    #pragma unroll
    for (int mi = 0; mi < 4; mi++)
        #pragma unroll
        for (int ni = 0; ni < 4; ni++)
            acc[mi][ni] = (f32x4){0.f, 0.f, 0.f, 0.f};

    const ushort* Ab = A  + (size_t)m0 * DD;
    const ushort* Bb = WT + (size_t)n0 * DD;

    for (int k0 = 0; k0 < DD; k0 += 32) {
        __syncthreads();
        #pragma unroll
        for (int j = 0; j < 2; j++) {
            const int rbase = (w * 2 + j) * 16;
            gload_lds16(Ab + (size_t)(rbase + srow) * DD + k0 + scol, &As[rbase * 32]);
            gload_lds16(Bb + (size_t)(rbase + srow) * DD + k0 + scol, &Bs[rbase * 32]);
        }
        __syncthreads();

        bf16x8 af[4], bfr[4];
        #pragma unroll
        for (int mi = 0; mi < 4; mi++)
            af[mi] = *(const bf16x8*)&As[(wr * 64 + mi * 16 + lr) * 32 + lg * 8];
        #pragma unroll
        for (int ni = 0; ni < 4; ni++)
            bfr[ni] = *(const bf16x8*)&Bs[(wc * 64 + ni * 16 + lr) * 32 + lg * 8];
        #pragma unroll
        for (int mi = 0; mi < 4; mi++)
            #pragma unroll
            for (int ni = 0; ni < 4; ni++)
                acc[mi][ni] = __builtin_amdgcn_mfma_f32_16x16x32_bf16(
                    af[mi], bfr[ni], acc[mi][ni], 0, 0, 0);
    }

    #pragma unroll
    for (int mi = 0; mi < 4; mi++) {
        #pragma unroll
        for (int ni = 0; ni < 4; ni++) {
            const int c  = n0 + wc * 64 + ni * 16 + lr;
            const float bc = bias[c];
            const int r0 = m0 + wr * 64 + mi * 16 + lg * 4;
            #pragma unroll
            for (int rg = 0; rg < 4; rg++)
                Cout[(size_t)(r0 + rg) * DD + c] = acc[mi][ni][rg] + bc;
        }
    }
}

// ---------------------------------------------------------------------------
// 4-warp swapped-QK^T flash attention, 64 q-rows/wave (2 q-groups).
// EXACT round-8 kernel (measured 84.7 us; best of 6 attn structure variants)
// ---------------------------------------------------------------------------
__global__ __launch_bounds__(256, 2) void flash_attn_mfma(
    const ushort* __restrict__ qh, const ushort* __restrict__ kh,
    const ushort* __restrict__ vt, ushort* __restrict__ ctx)
{
    __shared__ ushort smem[16384];   // K: 2x4096 | V: 2x4096 = 32 KB

    const int t  = threadIdx.x;
    const int w  = t >> 6;          // warp 0..3
    const int l  = t & 63;
    const int hi = l >> 5;          // half index
    const int lq = l & 31;          // q col / kv row / d row selector

    // bijective XCD-chunk swizzle: 512 wgs = 8 XCDs x 64
    const int wg = (blockIdx.x & 7) * 64 + (blockIdx.x >> 3);
    const int bi = wg >> 7;
    const int h  = (wg >> 3) & 15;
    const int q0 = (wg & 7) * 256;

    const size_t base  = (size_t)(bi * HH + h) * SS * HDD;  // [S][HD]
    const size_t basev = (size_t)(bi * HH + h) * HDD * SS;  // [HD][S]

    // Q B-frags, 2 q-groups: lane holds Q[q0+w*64+qg*32+lq][ds*16+hi*8+i]
    bf16x8 qf0[4], qf1[4];
    {
        const ushort* qp0 = qh + base + (size_t)(q0 + w * 64 + lq) * HDD;
        const ushort* qp1 = qp0 + 32 * HDD;
        #pragma unroll
        for (int ds = 0; ds < 4; ds++) {
            qf0[ds] = *(const bf16x8*)(qp0 + ds * 16 + hi * 8);
            qf1[ds] = *(const bf16x8*)(qp1 + ds * 16 + hi * 8);
        }
    }

    f32x16 o00 = {}, o01 = {}, o10 = {}, o11 = {};  // o[qg][d-half]
    float l0 = 0.f, l1 = 0.f;      // lane-local p-sums per q-group

    const int rsub = l >> 3;                    // 0..7
    const int csw  = ((l & 7) ^ rsub) * 8;      // pre-swizzled 16B chunk
    auto stageK = [&](int buf, int kv) {
        #pragma unroll
        for (int j = 0; j < 2; j++) {
            const int rb = 16 * w + 8 * j;
            gload_lds16(kh + base + (size_t)(kv + rb + rsub) * HDD + csw,
                        &smem[buf * 4096 + rb * 64]);
        }
    };
    auto stageV = [&](int buf, int kv) {
        #pragma unroll
        for (int j = 0; j < 2; j++) {
            const int rb = 16 * w + 8 * j;
            gload_lds16(vt + basev + (size_t)(rb + rsub) * SS + kv + csw,
                        &smem[8192 + buf * 4096 + rb * 64]);
        }
    };

    auto qk2 = [&](const ushort* KB, int kvh, f32x16& sg0, f32x16& sg1) {
        sg0 = (f32x16){};
        sg1 = (f32x16){};
        __builtin_amdgcn_s_setprio(1);
        #pragma unroll
        for (int ds = 0; ds < 4; ds++) {
            const int slot = ((ds * 2 + hi) ^ (l & 7)) * 8;
            bf16x8 ka = *(const bf16x8*)&KB[(kvh * 32 + lq) * 64 + slot];
            sg0 = __builtin_amdgcn_mfma_f32_32x32x16_bf16(ka, qf0[ds], sg0, 0, 0, 0);
            sg1 = __builtin_amdgcn_mfma_f32_32x32x16_bf16(ka, qf1[ds], sg1, 0, 0, 0);
        }
        __builtin_amdgcn_s_setprio(0);
    };

    auto finish16 = [&](f32x16& s, float& lacc, bf16x8* pa2) {
        float t0 = 0.f, t1 = 0.f, t2 = 0.f, t3 = 0.f;
        #pragma unroll
        for (int r = 0; r < 16; r += 4) {
            s[r + 0] = exp2_raw(s[r + 0]); t0 += s[r + 0];
            s[r + 1] = exp2_raw(s[r + 1]); t1 += s[r + 1];
            s[r + 2] = exp2_raw(s[r + 2]); t2 += s[r + 2];
            s[r + 3] = exp2_raw(s[r + 3]); t3 += s[r + 3];
        }
        lacc += (t0 + t1) + (t2 + t3);
        #pragma unroll
        for (int sblk = 0; sblk < 2; sblk++) {
            const int ob = sblk * 8;
            unsigned a = cvtpk(s[ob + 0], s[ob + 1]);
            unsigned b = cvtpk(s[ob + 4], s[ob + 5]);
            halfswap(a, b, hi);
            unsigned c = cvtpk(s[ob + 2], s[ob + 3]);
            unsigned d = cvtpk(s[ob + 6], s[ob + 7]);
            halfswap(c, d, hi);
            union { unsigned u[4]; bf16x8 v; } fr;
            fr.u[0] = a; fr.u[1] = c; fr.u[2] = b; fr.u[3] = d;
            pa2[sblk] = fr.v;
        }
    };

    auto pvhalf = [&](const ushort* VB, int kvh,
                      const bf16x8* pg0, const bf16x8* pg1) {
        __builtin_amdgcn_s_setprio(1);
        #pragma unroll
        for (int ksl = 0; ksl < 2; ksl++) {
            const int ks = kvh * 2 + ksl;
            const int slot = ((ks * 2 + hi) ^ (l & 7)) * 8;
            bf16x8 vb0 = *(const bf16x8*)&VB[lq * 64 + slot];
            bf16x8 vb1 = *(const bf16x8*)&VB[(32 + lq) * 64 + slot];
            o00 = __builtin_amdgcn_mfma_f32_32x32x16_bf16(pg0[ksl], vb0, o00, 0, 0, 0);
            o01 = __builtin_amdgcn_mfma_f32_32x32x16_bf16(pg0[ksl], vb1, o01, 0, 0, 0);
            o10 = __builtin_amdgcn_mfma_f32_32x32x16_bf16(pg1[ksl], vb0, o10, 0, 0, 0);
            o11 = __builtin_amdgcn_mfma_f32_32x32x16_bf16(pg1[ksl], vb1, o11, 0, 0, 0);
        }
        __builtin_amdgcn_s_setprio(0);
    };

    stageK(0, 0); stageV(0, 0);
    int cur = 0;

    for (int tt = 0; tt < 32; tt++) {
        PIPE_BAR(0);                 // tile tt in LDS (staged a full tile ago)
        if (tt + 1 < 32) { stageK(cur ^ 1, (tt + 1) * 64);
                           stageV(cur ^ 1, (tt + 1) * 64); }

        const ushort* KB = &smem[cur * 4096];
        const ushort* VB = &smem[8192 + cur * 4096];

        f32x16 sA, sB, sC, sD;       // h0:{g0,g1}, h1:{g0,g1}
        qk2(KB, 0, sA, sB);
        qk2(KB, 1, sC, sD);

        bf16x8 pg0[2], pg1[2];
        finish16(sA, l0, pg0);
        finish16(sB, l1, pg1);
        pvhalf(VB, 0, pg0, pg1);
        finish16(sC, l0, pg0);
        finish16(sD, l1, pg1);
        pvhalf(VB, 1, pg0, pg1);

        cur ^= 1;
    }

    const float ls0 = l0 + __shfl_xor(l0, 32);
    const float ls1 = l1 + __shfl_xor(l1, 32);
    const float iv0 = 1.0f / ls0;
    const float iv1 = 1.0f / ls1;
    #pragma unroll
    for (int r = 0; r < 16; r++) {
        const int qq = (r & 3) + 8 * (r >> 2) + 4 * hi;   // crow(r,hi)
        const float a0 = __shfl(iv0, qq);
        const float a1 = __shfl(iv1, qq);
        const int row0 = q0 + w * 64 + qq;
        ushort* op0 = ctx + (size_t)(bi * SS + row0) * DD + h * HDD;
        op0[lq]      = f2bf(o00[r] * a0);
        op0[32 + lq] = f2bf(o01[r] * a0);
        ushort* op1 = op0 + (size_t)32 * DD;
        op1[lq]      = f2bf(o10[r] * a1);
        op1[32 + lq] = f2bf(o11[r] * a1);
    }
}

// ---------------------------------------------------------------------------
extern "C" void kernel_launch(void* const* d_in, const int* in_sizes, int n_in,
                              void* d_out, int out_size, void* d_ws, size_t ws_size,
                              hipStream_t stream) {
    const float* q   = (const float*)d_in[0];
    const float* k   = (const float*)d_in[1];
    const float* v   = (const float*)d_in[2];
    const float* w_q = (const float*)d_in[3];
    const float* b_q = (const float*)d_in[4];
    const float* w_k = (const float*)d_in[5];
    const float* b_k = (const float*)d_in[6];
    const float* w_v = (const float*)d_in[7];
    const float* b_v = (const float*)d_in[8];
    const float* w_o = (const float*)d_in[9];
    const float* b_o = (const float*)d_in[10];
    float* out = (float*)d_out;

    const size_t SZ = (size_t)BB * SS * DD;   // 8388608
    const size_t WZ = (size_t)DD * DD;        // 1048576
    ushort* ws2  = (ushort*)d_ws;
    ushort* qh   = ws2;             // bf16 [B,H,S,HD], pre-scaled
    ushort* kh   = ws2 + SZ;        // bf16 [B,H,S,HD]
    ushort* vt   = ws2 + 2 * SZ;    // bf16 [B,H,HD,S]
    ushort* ctxb = ws2 + 3 * SZ;    // bf16 [B,S,D]
    ushort* wqT  = ws2 + 4 * SZ;    // bf16 [N][K]
    ushort* wkT  = wqT + WZ;
    ushort* wvT  = wkT + WZ;
    ushort* woT  = wvT + WZ;

    wtrans_k<<<dim3(32, 32, 4), 256, 0, stream>>>(w_q, w_k, w_v, w_o,
                                                  wqT, wkT, wvT, woT);

    gemm_qkv_k<<<dim3(1536), 256, 0, stream>>>(q, k, v, wqT, wkT, wvT,
                                               b_q, b_k, b_v, qh, kh, vt);

    flash_attn_mfma<<<dim3(512), 256, 0, stream>>>(qh, kh, vt, ctxb);

    gemm_out_k<<<dim3(512), 256, 0, stream>>>(ctxb, woT, b_o, out);
}